// Round 1
// 507.022 us; speedup vs baseline: 1.0029x; 1.0029x over previous
//
#include <hip/hip_runtime.h>
#include <stdint.h>

typedef __bf16 bf16_t;
typedef bf16_t bf16x8 __attribute__((ext_vector_type(8)));
typedef bf16_t bf16x4 __attribute__((ext_vector_type(4)));
typedef float f32x4 __attribute__((ext_vector_type(4)));

#define N_NODES 8192
#define DIM 512

typedef __attribute__((address_space(1))) void as1_void;
typedef __attribute__((address_space(3))) void as3_void;

// async global -> LDS, 16B per lane. LDS dest must be wave-uniform base + lane*16.
__device__ __forceinline__ void gload_lds16(const void* g, void* l) {
  __builtin_amdgcn_global_load_lds((as1_void*)g, (as3_void*)l, 16, 0, 0);
}

// ---- transpose + convert: x [8192,512] f32 -> xT [512,8192] bf16 ------------
__global__ __launch_bounds__(256) void k_transpose_x(const float* __restrict__ x,
                                                     bf16_t* __restrict__ xT) {
  __shared__ float tile[64][65];
  const int m0 = blockIdx.x * 64;
  const int n0 = blockIdx.y * 64;
  const int t = threadIdx.x;
  const int r = t >> 4;         // 0..15
  const int c = (t & 15) << 2;  // 0..60
#pragma unroll
  for (int i = 0; i < 4; ++i) {
    f32x4 v = *(const f32x4*)&x[(size_t)(m0 + r + i * 16) * DIM + n0 + c];
    tile[r + i * 16][c + 0] = v.x;
    tile[r + i * 16][c + 1] = v.y;
    tile[r + i * 16][c + 2] = v.z;
    tile[r + i * 16][c + 3] = v.w;
  }
  __syncthreads();
#pragma unroll
  for (int i = 0; i < 4; ++i) {
    const int rn = r + i * 16;
    bf16x4 o = {(bf16_t)tile[c + 0][rn], (bf16_t)tile[c + 1][rn],
                (bf16_t)tile[c + 2][rn], (bf16_t)tile[c + 3][rn]};
    *(bf16x4*)&xT[(size_t)(n0 + rn) * N_NODES + m0 + c] = o;
  }
}

// ---- convert W [512,512] f32 -> bf16 ---------------------------------------
__global__ __launch_bounds__(256) void k_cvt_w(const float* __restrict__ W,
                                               bf16_t* __restrict__ Wb) {
  const int t = blockIdx.x * 256 + threadIdx.x;
  f32x4 v = *(const f32x4*)&W[(size_t)t * 4];
  bf16x4 o = {(bf16_t)v.x, (bf16_t)v.y, (bf16_t)v.z, (bf16_t)v.w};
  *(bf16x4*)&Wb[(size_t)t * 4] = o;
}

// ---- GEMM1: P[s] = adj[:, s-chunk] @ xT[s-chunk, :]  (fp32 partials) --------
// m97 structure: 128x128 tile, BK=32, 256 thr = 4 waves (2x2), wave-tile 64x64,
// acc[4][4]. global_load_lds width-16 staging (A staged as fp32, cvt at read),
// double-buffered LDS, 1 barrier per K-step.
// LDS read swizzle (XOR), inverse-applied to the GLOBAL source (G21):
//   A (f32, 128B row):  phys_chunk = log_chunk ^ (row & 7)      -> 2-way max
//   B (bf16, 64B row):  phys_chunk = log_chunk ^ ((row>>1) & 3) -> 2-way max
template <int S>
__global__ __launch_bounds__(256, 3) void k_gemm1(const float* __restrict__ A,
                                                  const bf16_t* __restrict__ Bt,
                                                  float* __restrict__ P) {
  constexpr int K = N_NODES;
  constexpr int KC = K / S;
  constexpr int NIT = KC / 32;  // even for all S used
  __shared__ float As[2][128 * 32];   // 16 KB per buf
  __shared__ bf16_t Bs[2][128 * 32];  // 8 KB per buf

  const int b = blockIdx.x;
  const int xcd = b & 7;
  const int i6 = b >> 3;
  const int n_tile = i6 & 3;
  const int s = (i6 >> 2) & (S - 1);
  const int mg = (i6 >> 2) / S;
  const int m0 = (mg * 8 + xcd) * 128;
  const int n0 = n_tile * 128;

  const int t = threadIdx.x;
  const int lane = t & 63;
  const int w = t >> 6;
  const int wr = w & 1;   // wave row: 64 rows
  const int wc = w >> 1;  // wave col: 64 cols
  const int lrow = lane & 15;
  const int quad = lane >> 4;

  // Staging source addresses. Per 16B slot: A row = slot>>3, B row = slot>>2.
  // Source chunk index carries the inverse swizzle (mask is i-independent since
  // i*32 ≡ 0 mod 8 for A rows and i*64 ≡ 0 mod 8 for B rows).
  const int aoff = ((t & 7) ^ ((t >> 3) & 7)) * 4;  // f32 col in [0,32)
  const int boff = ((t & 3) ^ ((t >> 3) & 3)) * 8;  // bf16 col in [0,32)
  const float* ag = A + (size_t)(m0 + (t >> 3)) * K + (size_t)s * KC + aoff;
  const bf16_t* bg = Bt + (size_t)(n0 + (t >> 2)) * K + (size_t)s * KC + boff;

  auto stage = [&](int it, int buf) {
    const int kc = it * 32;
#pragma unroll
    for (int i = 0; i < 4; ++i)  // A: 1024 slots = 256 thr x 4
      gload_lds16(ag + (size_t)(i * 32) * K + kc, &As[buf][(i * 256 + t) * 4]);
#pragma unroll
    for (int i = 0; i < 2; ++i)  // B: 512 slots = 256 thr x 2
      gload_lds16(bg + (size_t)(i * 64) * K + kc, &Bs[buf][(i * 256 + t) * 8]);
  };

  // Swizzled read offsets (per-thread constants).
  // A: logical chunks quad*2 and quad*2+1 of a 8-chunk row; row&7 == lrow&7.
  const int apc0 = ((quad * 2) ^ (lrow & 7)) * 4;
  const int apc1 = (((quad * 2) ^ (lrow & 7)) ^ 1) * 4;
  // B: logical chunk = quad of a 4-chunk row; (row>>1)&3 == (lrow>>1)&3.
  const int bpc = (quad ^ ((lrow >> 1) & 3)) * 8;

  f32x4 acc[4][4] = {};

  auto compute = [&](int buf) {
    bf16x8 af[4], bfr[4];
#pragma unroll
    for (int ii = 0; ii < 4; ++ii) {
      const int rb = (wr * 64 + ii * 16 + lrow) * 32;
      f32x4 a0 = *(const f32x4*)&As[buf][rb + apc0];
      f32x4 a1 = *(const f32x4*)&As[buf][rb + apc1];
#pragma unroll
      for (int z = 0; z < 4; ++z) {
        af[ii][z] = (bf16_t)a0[z];
        af[ii][z + 4] = (bf16_t)a1[z];
      }
    }
#pragma unroll
    for (int jj = 0; jj < 4; ++jj)
      bfr[jj] = *(const bf16x8*)&Bs[buf][(wc * 64 + jj * 16 + lrow) * 32 + bpc];
#pragma unroll
    for (int ii = 0; ii < 4; ++ii)
#pragma unroll
      for (int jj = 0; jj < 4; ++jj)
        acc[ii][jj] =
            __builtin_amdgcn_mfma_f32_16x16x32_bf16(af[ii], bfr[jj], acc[ii][jj], 0, 0, 0);
  };

  stage(0, 0);
  __syncthreads();
#pragma unroll 1
  for (int it = 0; it < NIT; it += 2) {
    stage(it + 1, 1);  // issue DMA before ds_read/MFMA (T3 minimum pattern)
    compute(0);
    __syncthreads();
    if (it + 2 < NIT) stage(it + 2, 0);
    compute(1);
    __syncthreads();
  }

  float* Pp = P + (size_t)s * N_NODES * DIM;
#pragma unroll
  for (int ii = 0; ii < 4; ++ii)
#pragma unroll
    for (int jj = 0; jj < 4; ++jj) {
      const int col = n0 + wc * 64 + jj * 16 + lrow;
#pragma unroll
      for (int r = 0; r < 4; ++r) {
        const int row = m0 + wr * 64 + ii * 16 + quad * 4 + r;
        Pp[(size_t)row * DIM + col] = acc[ii][jj][r];
      }
    }
}

// ---- GEMM2: out = relu((sum_s P[s]) @ W^T + b), fp32 out --------------------
// 64x128 tile, BK=64, 256 thr = 4 waves (2x2), wave-tile 32x64. K=512 only.
// Grid remapped so the 4 n-tiles of one m-band share an XCD (P L2 reuse).
template <int S>
__global__ __launch_bounds__(256, 2) void k_gemm2(const float* __restrict__ P,
                                                  const bf16_t* __restrict__ Bw,
                                                  const float* __restrict__ bias,
                                                  float* __restrict__ out) {
  constexpr int K = DIM;
  constexpr int LDA = 72;
  constexpr int LDB = 72;
  constexpr size_t PS = (size_t)N_NODES * DIM;
  __shared__ bf16_t As[64 * LDA];
  __shared__ bf16_t Bs[128 * LDB];

  const int b = blockIdx.x;
  const int xcd = b & 7;                        // m-band fixed per XCD
  const int j = b >> 3;
  const int n0 = (j & 3) * 128;                 // same-m n-tiles adjacent in time
  const int m0 = ((j >> 2) * 8 + xcd) * 64;
  const int t = threadIdx.x;
  const int lane = t & 63;
  const int w = t >> 6;
  const int wr = w & 1;
  const int wc = w >> 1;
  const int lrow = lane & 15;
  const int quad = lane >> 4;
  const int ar = t >> 2, aq = t & 3;  // A: 64 rows, 16 f32 at aq*16
  const int br = t >> 1, bq = t & 1;  // B: 128 rows, 32 bf16 at bq*32

  const float* ap = P + (size_t)(m0 + ar) * K + aq * 16;
  const bf16_t* bp = Bw + (size_t)(n0 + br) * K + bq * 32;
  bf16_t* aw = &As[ar * LDA + aq * 16];
  bf16_t* bw = &Bs[br * LDB + bq * 32];

  f32x4 acc[2][4] = {};

  for (int k0 = 0; k0 < K; k0 += 64) {
    f32x4 av[4];
#pragma unroll
    for (int z = 0; z < 4; ++z) av[z] = *(const f32x4*)(ap + k0 + z * 4);
#pragma unroll
    for (int s2 = 1; s2 < S; ++s2)
#pragma unroll
      for (int z = 0; z < 4; ++z) av[z] += *(const f32x4*)(ap + s2 * PS + k0 + z * 4);
    bf16x8 b0 = *(const bf16x8*)(bp + k0);
    bf16x8 b1 = *(const bf16x8*)(bp + k0 + 8);
    bf16x8 b2 = *(const bf16x8*)(bp + k0 + 16);
    bf16x8 b3 = *(const bf16x8*)(bp + k0 + 24);
    bf16x8 a0, a1;
#pragma unroll
    for (int z = 0; z < 4; ++z) {
      a0[z] = (bf16_t)av[0][z];
      a0[z + 4] = (bf16_t)av[1][z];
      a1[z] = (bf16_t)av[2][z];
      a1[z + 4] = (bf16_t)av[3][z];
    }
    __syncthreads();
    *(bf16x8*)aw = a0;
    *(bf16x8*)(aw + 8) = a1;
    *(bf16x8*)bw = b0;
    *(bf16x8*)(bw + 8) = b1;
    *(bf16x8*)(bw + 16) = b2;
    *(bf16x8*)(bw + 24) = b3;
    __syncthreads();
#pragma unroll
    for (int kk = 0; kk < 64; kk += 32) {
      bf16x8 af0 = *(const bf16x8*)&As[(wr * 32 + 0 + lrow) * LDA + kk + quad * 8];
      bf16x8 af1 = *(const bf16x8*)&As[(wr * 32 + 16 + lrow) * LDA + kk + quad * 8];
      bf16x8 bf0 = *(const bf16x8*)&Bs[(wc * 64 + 0 + lrow) * LDB + kk + quad * 8];
      bf16x8 bf1 = *(const bf16x8*)&Bs[(wc * 64 + 16 + lrow) * LDB + kk + quad * 8];
      bf16x8 bf2 = *(const bf16x8*)&Bs[(wc * 64 + 32 + lrow) * LDB + kk + quad * 8];
      bf16x8 bf3 = *(const bf16x8*)&Bs[(wc * 64 + 48 + lrow) * LDB + kk + quad * 8];
      acc[0][0] = __builtin_amdgcn_mfma_f32_16x16x32_bf16(af0, bf0, acc[0][0], 0, 0, 0);
      acc[0][1] = __builtin_amdgcn_mfma_f32_16x16x32_bf16(af0, bf1, acc[0][1], 0, 0, 0);
      acc[0][2] = __builtin_amdgcn_mfma_f32_16x16x32_bf16(af0, bf2, acc[0][2], 0, 0, 0);
      acc[0][3] = __builtin_amdgcn_mfma_f32_16x16x32_bf16(af0, bf3, acc[0][3], 0, 0, 0);
      acc[1][0] = __builtin_amdgcn_mfma_f32_16x16x32_bf16(af1, bf0, acc[1][0], 0, 0, 0);
      acc[1][1] = __builtin_amdgcn_mfma_f32_16x16x32_bf16(af1, bf1, acc[1][1], 0, 0, 0);
      acc[1][2] = __builtin_amdgcn_mfma_f32_16x16x32_bf16(af1, bf2, acc[1][2], 0, 0, 0);
      acc[1][3] = __builtin_amdgcn_mfma_f32_16x16x32_bf16(af1, bf3, acc[1][3], 0, 0, 0);
    }
  }

#pragma unroll
  for (int i = 0; i < 2; ++i)
#pragma unroll
    for (int j2 = 0; j2 < 4; ++j2) {
      const int col = n0 + wc * 64 + j2 * 16 + lrow;
      const float bj = bias[col];
#pragma unroll
      for (int r = 0; r < 4; ++r) {
        const int row = m0 + wr * 32 + i * 16 + quad * 4 + r;
        float v = acc[i][j2][r] + bj;
        out[(size_t)row * DIM + col] = v > 0.0f ? v : 0.0f;
      }
    }
}

extern "C" void kernel_launch(void* const* d_in, const int* in_sizes, int n_in,
                              void* d_out, int out_size, void* d_ws, size_t ws_size,
                              hipStream_t stream) {
  const float* x = (const float*)d_in[0];    // [8192,512]
  const float* adj = (const float*)d_in[1];  // [8192,8192]
  const float* W = (const float*)d_in[2];    // [512,512]
  const float* b = (const float*)d_in[3];    // [512]
  float* out = (float*)d_out;

  // ws layout: xT (8 MB bf16) | Wb (0.5 MB bf16) | P (S x 16 MB f32)
  bf16_t* xT = (bf16_t*)d_ws;
  bf16_t* Wb = xT + (size_t)DIM * N_NODES;
  float* P = (float*)(Wb + (size_t)DIM * DIM);
  const size_t base = (size_t)DIM * N_NODES * 2 + (size_t)DIM * DIM * 2;
  const size_t pslab = (size_t)N_NODES * DIM * 4;

  k_transpose_x<<<dim3(N_NODES / 64, DIM / 64), 256, 0, stream>>>(x, xT);
  k_cvt_w<<<dim3((DIM * DIM / 4) / 256), 256, 0, stream>>>(W, Wb);

  if (ws_size >= base + 4 * pslab) {
    k_gemm1<4><<<dim3(256 * 4), 256, 0, stream>>>(adj, xT, P);
    k_gemm2<4><<<dim3(512), 256, 0, stream>>>(P, Wb, b, out);
  } else {
    k_gemm1<1><<<dim3(256), 256, 0, stream>>>(adj, xT, P);
    k_gemm2<1><<<dim3(512), 256, 0, stream>>>(P, Wb, b, out);
  }
}